// Round 11
// baseline (1744.810 us; speedup 1.0000x reference)
//
#include <hip/hip_runtime.h>
#include <cstdint>

// ---------------------------------------------------------------------------
// JukeboxAutoEncoder fp32, round 18.
// r17 post-mortem: up TPL=2 flat dur, WRITE_SIZE 65->120MB (write-amp) ->
//   reverted up to r10. Drain-amortization 0-for-3: conv stall is the staging
//   transpose + read-XOR, not drain count.
// This round: ENCODER intermediates -> channel-major [c][t]. Staging becomes
//   coalesced row copy (aligned ds_write_b128, conflict-free), reads lose the
//   ^swz XOR, stores stay coalesced (float2 along t). All fmaf chains / ci
//   order / tap values / zero-pad BIT-IDENTICAL (r15 frozen-order lesson).
//   z_e lands [c][t]: vq_dots z-staging becomes direct copy (z reads are
//   broadcast -> no conflict); nz/vq_finish keep exact lane=c + shuffle trees
//   (bit-exact) with scattered L2-warm loads. z_q still [tok][c] -> decoder
//   (conv3/up/proj) is verbatim r10.
// Output layout (flat f32): x_hat[262144] | loss_vq[1] | ids[32768] | sim[16777216]
// ---------------------------------------------------------------------------

#define OFF_LOSS 262144
#define OFF_IDS  262145
#define OFF_SIM  294913

// ---------------- down0ct: (B,65536,1) -> [b][co][32768], K=4 s2, relu ----
// grid (128, 64, 4) = (t-chunk, co, b); co wave-uniform -> s_load weights.
__global__ __launch_bounds__(256) void down0ct_kernel(
    const float* __restrict__ x, const float* __restrict__ w,
    const float* __restrict__ bias, float* __restrict__ y)
{
  const int t  = blockIdx.x * 256 + threadIdx.x;
  const int co = blockIdx.y;
  const int b  = blockIdx.z;
  const float* xb = x + (size_t)b * 65536;
  float acc = bias[co];
  #pragma unroll
  for (int k = 0; k < 4; ++k) {
    int gt = 2 * t - 1 + k;
    float xv = ((unsigned)gt < 65536u) ? xb[gt] : 0.f;
    acc += xv * w[k * 64 + co];
  }
  y[((size_t)b * 64 + co) * 32768 + t] = fmaxf(acc, 0.f);
}

// ---------------- conv3ct: K=3, dil DIL, [c][t] in/out, relu, +res --------
// 512 thr = 8 waves; wave wv owns co0 = wv*8 (s_load weights, r10 inner loop
// verbatim). LDS col c <-> global t = t0 - 4 + c (16B-aligned staging).
template <int DIL, bool HAS_RES, int TT>
__global__ __launch_bounds__(512, 8) void conv3ct_kernel(
    const float* __restrict__ x, const float* __restrict__ w,
    const float* __restrict__ bias, const float* res,
    float* y, int T)
{
  constexpr int TPL = TT / 64;               // 1 or 2 t per lane
  constexpr int XT  = TT + 8;                // staged cols (t0-4 .. t0+TT+4)
  constexpr int XS  = ((XT - 1) | 7) + 1;    // 136 or 72 (mult of 8)
  constexpr int NCH = XT / 4;                // float4 chunks per row
  constexpr int NV  = TPL + 2 * DIL;
  __shared__ float xs[64 * XS];
  const int tid  = threadIdx.x;
  const int lane = tid & 63;
  const int b    = blockIdx.y;
  const int t0   = blockIdx.x * TT;
  const int wv   = __builtin_amdgcn_readfirstlane(tid >> 6);
  const int co0  = __builtin_amdgcn_readfirstlane(wv * 8);

  // stage rows [ci][t0-4 .. ) -- coalesced float4, aligned b128 LDS writes
  for (int e = tid; e < 64 * NCH; e += 512) {
    int row = e / NCH, ch = e - row * NCH;
    int gt  = t0 - 4 + ch * 4;
    const float* src = x + ((size_t)b * 64 + row) * T + gt;
    float4 v;
    if (gt >= 0 && gt + 3 < T) {
      v = *(const float4*)src;
    } else {
      v.x = ((unsigned)(gt + 0) < (unsigned)T) ? src[0] : 0.f;
      v.y = ((unsigned)(gt + 1) < (unsigned)T) ? src[1] : 0.f;
      v.z = ((unsigned)(gt + 2) < (unsigned)T) ? src[2] : 0.f;
      v.w = ((unsigned)(gt + 3) < (unsigned)T) ? src[3] : 0.f;
    }
    *(float4*)&xs[row * XS + ch * 4] = v;
  }
  __syncthreads();

  float acc[TPL][8] = {};
  const float* wb = w + co0;                 // w[k][ci][co0..co0+7]
  const int tb = TPL * lane;
  for (int ci = 0; ci < 64; ++ci) {
    const float* xr = xs + ci * XS;
    float xv[NV];                            // xv[j] <-> t = t0 + tb - DIL + j
    if constexpr (TPL == 2) {                // even base -> ds_read_b64 pairs
      float xq[NV + 2];
      const int sp = tb + 3 - DIL;           // even (tb even, DIL odd)
      #pragma unroll
      for (int q = 0; q < NV / 2 + 1; ++q) {
        float2 v = *(const float2*)&xr[sp + 2 * q];
        xq[2 * q] = v.x; xq[2 * q + 1] = v.y;
      }
      #pragma unroll
      for (int j = 0; j < NV; ++j) xv[j] = xq[j + 1];
    } else {
      const int s0 = tb + 4 - DIL;
      #pragma unroll
      for (int j = 0; j < NV; ++j) xv[j] = xr[s0 + j];
    }
    const float* w0 = wb + (0 * 64 + ci) * 64;
    const float* w1 = wb + (1 * 64 + ci) * 64;
    const float* w2 = wb + (2 * 64 + ci) * 64;
    #pragma unroll
    for (int j = 0; j < 8; ++j) {            // r10 fmaf nest, bit-identical
      float c0 = w0[j], c1 = w1[j], c2 = w2[j];
      #pragma unroll
      for (int i = 0; i < TPL; ++i)
        acc[i][j] = fmaf(xv[i], c0, fmaf(xv[i + DIL], c1, fmaf(xv[i + 2 * DIL], c2, acc[i][j])));
    }
  }

  float bs[8];
  #pragma unroll
  for (int j = 0; j < 8; ++j) bs[j] = bias[co0 + j];
  #pragma unroll
  for (int j = 0; j < 8; ++j) {              // [c][t] store: coalesced per row
    float rr[TPL];
    #pragma unroll
    for (int i = 0; i < TPL; ++i) rr[i] = fmaxf(acc[i][j] + bs[j], 0.f);
    size_t o = ((size_t)b * 64 + co0 + j) * T + t0 + tb;
    if (HAS_RES) {
      if constexpr (TPL == 2) {
        float2 rv = *(const float2*)&res[o];
        rr[0] += rv.x; rr[1] += rv.y;
      } else {
        rr[0] += res[o];
      }
    }
    if constexpr (TPL == 2) *(float2*)&y[o] = make_float2(rr[0], rr[1]);
    else                    y[o] = rr[0];
  }
}

// ---------------- down2ct: K=4 stride2, [c][t] in/out, relu ---------------
__global__ __launch_bounds__(512, 8) void down2ct_kernel(
    const float* __restrict__ x, const float* __restrict__ w,
    const float* __restrict__ bias, float* __restrict__ y, int Tin)
{
  constexpr int XT = 136, XS = 136, NCH = 34; // cols: t = 2*t0 - 4 + c
  __shared__ float xs[64 * XS];
  const int tid  = threadIdx.x;
  const int lane = tid & 63;
  const int b    = blockIdx.y;
  const int t0   = blockIdx.x * 64;
  const int Tout = Tin >> 1;
  const int wv   = __builtin_amdgcn_readfirstlane(tid >> 6);
  const int co0  = __builtin_amdgcn_readfirstlane(wv * 8);

  for (int e = tid; e < 64 * NCH; e += 512) {
    int row = e / NCH, ch = e - row * NCH;
    int gt  = 2 * t0 - 4 + ch * 4;
    const float* src = x + ((size_t)b * 64 + row) * Tin + gt;
    float4 v;
    if (gt >= 0 && gt + 3 < Tin) {
      v = *(const float4*)src;
    } else {
      v.x = ((unsigned)(gt + 0) < (unsigned)Tin) ? src[0] : 0.f;
      v.y = ((unsigned)(gt + 1) < (unsigned)Tin) ? src[1] : 0.f;
      v.z = ((unsigned)(gt + 2) < (unsigned)Tin) ? src[2] : 0.f;
      v.w = ((unsigned)(gt + 3) < (unsigned)Tin) ? src[3] : 0.f;
    }
    *(float4*)&xs[row * XS + ch * 4] = v;
  }
  __syncthreads();

  float acc[8] = {};
  const float* wb = w + co0;
  for (int ci = 0; ci < 64; ++ci) {
    const float* xr = xs + ci * XS;
    float xq[6];                             // cols 2*lane+2 .. 2*lane+7
    #pragma unroll
    for (int q = 0; q < 3; ++q) {
      float2 v = *(const float2*)&xr[2 * lane + 2 + 2 * q];
      xq[2 * q] = v.x; xq[2 * q + 1] = v.y;
    }
    float a0 = xq[1], a1 = xq[2], a2 = xq[3], a3 = xq[4];  // t=2(t0+l)-1+..
    const float* w0 = wb + (0 * 64 + ci) * 64;
    const float* w1 = wb + (1 * 64 + ci) * 64;
    const float* w2 = wb + (2 * 64 + ci) * 64;
    const float* w3 = wb + (3 * 64 + ci) * 64;
    #pragma unroll
    for (int j = 0; j < 8; ++j)
      acc[j] = fmaf(a0, w0[j], fmaf(a1, w1[j], fmaf(a2, w2[j], fmaf(a3, w3[j], acc[j]))));
  }

  #pragma unroll
  for (int j = 0; j < 8; ++j) {
    size_t o = ((size_t)b * 64 + co0 + j) * Tout + t0 + lane;
    y[o] = fmaxf(acc[j] + bias[co0 + j], 0.f);
  }
}

// ---------------- conv3: decoder r10 version ([t][c], transpose staging) --
template <int DIL, bool HAS_RES, int TT>
__global__ __launch_bounds__(512, 8) void conv3_kernel(
    const float* __restrict__ x, const float* __restrict__ w,
    const float* __restrict__ bias, const float* res,
    float* y, int T)
{
  constexpr int TPL = TT / 64;
  constexpr int XT  = TT + 2 * DIL;
  constexpr int XS  = ((XT - 1) | 15) + 1;
  constexpr int NV  = TPL + 2 * DIL;
  __shared__ float xs[64 * XS];
  const int tid  = threadIdx.x;
  const int lane = tid & 63;
  const int b    = blockIdx.y;
  const int t0   = blockIdx.x * TT;
  const int wv   = __builtin_amdgcn_readfirstlane(tid >> 6);
  const int co0  = __builtin_amdgcn_readfirstlane(wv * 8);

  const float* xb = x + (size_t)b * T * 64;
  for (int e = tid; e < 16 * XT; e += 512) {
    int tl = e >> 4, cq = (e & 15) * 4;
    int cs = tl ^ (((cq >> 2) & 7) << 1);
    int gt = t0 - DIL + tl;
    float4 v = make_float4(0.f, 0.f, 0.f, 0.f);
    if ((unsigned)gt < (unsigned)T) v = *(const float4*)&xb[(size_t)gt * 64 + cq];
    xs[(cq + 0) * XS + cs] = v.x;
    xs[(cq + 1) * XS + cs] = v.y;
    xs[(cq + 2) * XS + cs] = v.z;
    xs[(cq + 3) * XS + cs] = v.w;
  }
  __syncthreads();

  float acc[TPL][8] = {};
  const float* wb = w + co0;
  const int tb = TPL * lane;
  for (int ci = 0; ci < 64; ++ci) {
    const int swz = ((ci >> 2) & 7) << 1;
    const float* xr = xs + ci * XS;
    float xv[NV];
    if constexpr (TPL == 2) {
      #pragma unroll
      for (int q = 0; q < NV / 2; ++q) {
        float2 v = *(const float2*)&xr[(tb + 2 * q) ^ swz];
        xv[2*q] = v.x; xv[2*q+1] = v.y;
      }
    } else {
      #pragma unroll
      for (int j = 0; j < NV; ++j) xv[j] = xr[(tb + j) ^ swz];
    }
    const float* w0 = wb + (0 * 64 + ci) * 64;
    const float* w1 = wb + (1 * 64 + ci) * 64;
    const float* w2 = wb + (2 * 64 + ci) * 64;
    #pragma unroll
    for (int j = 0; j < 8; ++j) {
      float c0 = w0[j], c1 = w1[j], c2 = w2[j];
      #pragma unroll
      for (int i = 0; i < TPL; ++i)
        acc[i][j] = fmaf(xv[i], c0, fmaf(xv[i + DIL], c1, fmaf(xv[i + 2 * DIL], c2, acc[i][j])));
    }
  }

  float bs[8];
  #pragma unroll
  for (int j = 0; j < 8; ++j) bs[j] = bias[co0 + j];
  #pragma unroll
  for (int i = 0; i < TPL; ++i) {
    size_t o = ((size_t)b * T + t0 + tb + i) * 64 + co0;
    float r[8];
    #pragma unroll
    for (int j = 0; j < 8; ++j) r[j] = fmaxf(acc[i][j] + bs[j], 0.f);
    if (HAS_RES) {
      float4 v0 = *(const float4*)&res[o];
      float4 v1 = *(const float4*)&res[o + 4];
      r[0] += v0.x; r[1] += v0.y; r[2] += v0.z; r[3] += v0.w;
      r[4] += v1.x; r[5] += v1.y; r[6] += v1.z; r[7] += v1.w;
    }
    *(float4*)&y[o]     = make_float4(r[0], r[1], r[2], r[3]);
    *(float4*)&y[o + 4] = make_float4(r[4], r[5], r[6], r[7]);
  }
}

// ---------------- up: conv_transpose K=4 stride2, 64->64, relu (r10) ------
__global__ __launch_bounds__(512, 8) void up_kernel(
    const float* __restrict__ x, const float* __restrict__ w,
    const float* __restrict__ bias, float* __restrict__ y, int Tin)
{
  constexpr int XT = 66, XS = 80;
  __shared__ float xs[64 * XS];
  const int tid  = threadIdx.x;
  const int lane = tid & 63;
  const int b    = blockIdx.y;
  const int u0   = blockIdx.x * 64;
  const int Tout = Tin << 1;
  const int wv   = __builtin_amdgcn_readfirstlane(tid >> 6);
  const int co0  = __builtin_amdgcn_readfirstlane(wv * 8);

  const float* xb = x + (size_t)b * Tin * 64;
  for (int e = tid; e < 16 * XT; e += 512) {
    int ul = e >> 4, cq = (e & 15) * 4;
    int cs = ul ^ (((cq >> 2) & 7) << 1);
    int gu = u0 - 1 + ul;
    float4 v = make_float4(0.f, 0.f, 0.f, 0.f);
    if ((unsigned)gu < (unsigned)Tin) v = *(const float4*)&xb[(size_t)gu * 64 + cq];
    xs[(cq + 0) * XS + cs] = v.x;
    xs[(cq + 1) * XS + cs] = v.y;
    xs[(cq + 2) * XS + cs] = v.z;
    xs[(cq + 3) * XS + cs] = v.w;
  }
  __syncthreads();

  float acce[8] = {}, acco[8] = {};
  const float* wb = w + co0;
  for (int ci = 0; ci < 64; ++ci) {
    const int swz = ((ci >> 2) & 7) << 1;
    const float* xr = xs + ci * XS;
    float a0 = xr[(lane) ^ swz];
    float a1 = xr[(lane + 1) ^ swz];
    float a2 = xr[(lane + 2) ^ swz];
    const float* w0 = wb + (0 * 64 + ci) * 64;
    const float* w1 = wb + (1 * 64 + ci) * 64;
    const float* w2 = wb + (2 * 64 + ci) * 64;
    const float* w3 = wb + (3 * 64 + ci) * 64;
    #pragma unroll
    for (int j = 0; j < 8; ++j) {
      acce[j] = fmaf(a0, w0[j], fmaf(a1, w2[j], acce[j]));
      acco[j] = fmaf(a1, w1[j], fmaf(a2, w3[j], acco[j]));
    }
  }

  size_t oe = ((size_t)b * Tout + 2 * (u0 + lane)) * 64 + co0;
  size_t oo = oe + 64;
  #pragma unroll
  for (int q = 0; q < 2; ++q) {
    float4 re, ro;
    re.x = fmaxf(acce[4*q+0] + bias[co0 + 4*q+0], 0.f);
    re.y = fmaxf(acce[4*q+1] + bias[co0 + 4*q+1], 0.f);
    re.z = fmaxf(acce[4*q+2] + bias[co0 + 4*q+2], 0.f);
    re.w = fmaxf(acce[4*q+3] + bias[co0 + 4*q+3], 0.f);
    ro.x = fmaxf(acco[4*q+0] + bias[co0 + 4*q+0], 0.f);
    ro.y = fmaxf(acco[4*q+1] + bias[co0 + 4*q+1], 0.f);
    ro.z = fmaxf(acco[4*q+2] + bias[co0 + 4*q+2], 0.f);
    ro.w = fmaxf(acco[4*q+3] + bias[co0 + 4*q+3], 0.f);
    *(float4*)&y[oe + 4 * q] = re;
    *(float4*)&y[oo + 4 * q] = ro;
  }
}

// ---------------- proj: K=3 dil1, 64->1, linear ---------------------------
__global__ __launch_bounds__(256) void proj_kernel(
    const float* __restrict__ x, const float* __restrict__ w,
    const float* __restrict__ bias, float* __restrict__ out)
{
  const int lane = threadIdx.x & 63;
  const int wid  = (blockIdx.x * 256 + threadIdx.x) >> 6;
  const float w0 = w[lane], w1 = w[64 + lane], w2 = w[128 + lane];
  const float bb = bias[0];
  size_t base = (size_t)wid * 64;
  for (int i = 0; i < 64; ++i) {
    size_t tau = base + i;
    int b = (int)(tau >> 16);
    int t = (int)(tau & 65535);
    const float* xb = x + ((size_t)b * 65536) * 64;
    float pm = (t > 0)     ? xb[(size_t)(t - 1) * 64 + lane] : 0.f;
    float pc =               xb[(size_t)t * 64 + lane];
    float pp = (t < 65535) ? xb[(size_t)(t + 1) * 64 + lane] : 0.f;
    float s = pm * w0 + pc * w1 + pp * w2;
    #pragma unroll
    for (int off = 32; off; off >>= 1) s += __shfl_down(s, off);
    if (lane == 0) out[tau] = s + bb;
  }
}

// ---------------- nz: per-token sum of squares (z_e is [b][c][8192]) ------
__global__ __launch_bounds__(256) void nz_kernel(
    const float* __restrict__ ze, float* __restrict__ nz)
{
  int lane = threadIdx.x & 63;
  int tok  = (blockIdx.x * 256 + threadIdx.x) >> 6;
  int b = tok >> 13, t = tok & 8191;
  float v = ze[((size_t)b * 64 + lane) * 8192 + t];   // same lane=c mapping
  float s = v * v;
  #pragma unroll
  for (int off = 32; off; off >>= 1) s += __shfl_down(s, off);
  if (lane == 0) nz[tok] = s;
}

// ---------------- ne: per-entry codebook norm (512 entries, once) ---------
__global__ __launch_bounds__(256) void ne_kernel(
    const float* __restrict__ cb, float* __restrict__ ne)
{
  int c = blockIdx.x * 256 + threadIdx.x;
  const float4* p = (const float4*)(cb + (size_t)c * 64);
  float s = 0.f;
  #pragma unroll
  for (int q = 0; q < 16; ++q) {
    float4 v = p[q];
    s += v.x * v.x + v.y * v.y + v.z * v.z + v.w * v.w;
  }
  ne[c] = s;
}

// ---------------- vq_dots: register-blocked GEMM, z_e [c][t] --------------
// zt staging = direct coalesced copy (no transpose, no swizzle needed:
// z-reads are 16-lane broadcast). ct staging unchanged (swizzled transpose).
__global__ __launch_bounds__(256) void vq_dots_kernel(
    const float* __restrict__ ze, const float* __restrict__ cb,
    const float* __restrict__ nzbuf, const float* __restrict__ nebuf,
    float* __restrict__ sim_out, float2* __restrict__ pmin)
{
  constexpr int ZS = 68, CS = 132;
  __shared__ float zt[64 * ZS];              // [d][tok]
  __shared__ float ct[64 * CS];              // [d][ent]
  const int tid = threadIdx.x;
  const int tx  = tid & 15;
  const int ty  = tid >> 4;
  const int bx  = blockIdx.x, by = blockIdx.y;

  {
    const int bb_ = bx >> 7;                 // token tile -> batch
    const int tr  = (bx & 127) * 64;         // t offset inside batch
    const float* zb = ze + ((size_t)bb_ * 64) * 8192 + tr;
    #pragma unroll
    for (int it = 0; it < 4; ++it) {         // 64 d x 16 float4-chunks
      int e = tid + it * 256;
      int d = e >> 4, ch = (e & 15) * 4;
      float4 v = *(const float4*)&zb[(size_t)d * 8192 + ch];
      *(float4*)&zt[d * ZS + ch] = v;
    }
    const float* cbb = cb + (size_t)by * 128 * 64;
    #pragma unroll
    for (int it = 0; it < 8; ++it) {
      int e = tid + it * 256;
      int el = e >> 4, cq = (e & 15) * 4;
      int cs = el ^ (((cq >> 2) & 7) << 2);
      float4 v = *(const float4*)&cbb[el * 64 + cq];
      ct[(cq + 0) * CS + cs] = v.x;
      ct[(cq + 1) * CS + cs] = v.y;
      ct[(cq + 2) * CS + cs] = v.z;
      ct[(cq + 3) * CS + cs] = v.w;
    }
  }
  __syncthreads();

  float acc[4][8] = {};
  #pragma unroll 4
  for (int k = 0; k < 64; ++k) {
    const int swz = ((k >> 2) & 7) << 2;
    float4 zv = *(const float4*)&zt[k * ZS + ty * 4];          // broadcast
    float4 c0 = *(const float4*)&ct[k * CS + ((tx * 8) ^ swz)];
    float4 c1 = *(const float4*)&ct[k * CS + ((tx * 8 + 4) ^ swz)];
    float zr[4] = {zv.x, zv.y, zv.z, zv.w};
    float cr[8] = {c0.x, c0.y, c0.z, c0.w, c1.x, c1.y, c1.z, c1.w};
    #pragma unroll
    for (int i = 0; i < 4; ++i)
      #pragma unroll
      for (int j = 0; j < 8; ++j)
        acc[i][j] = fmaf(zr[i], cr[j], acc[i][j]);
  }

  float4 nzq = *(const float4*)&nzbuf[bx * 64 + ty * 4];
  float nzv[4] = {nzq.x, nzq.y, nzq.z, nzq.w};
  float4 ne0  = *(const float4*)&nebuf[by * 128 + tx * 8];
  float4 ne1  = *(const float4*)&nebuf[by * 128 + tx * 8 + 4];
  float nev[8]  = {ne0.x, ne0.y, ne0.z, ne0.w, ne1.x, ne1.y, ne1.z, ne1.w};
  float rsne[8];
  #pragma unroll
  for (int j = 0; j < 8; ++j) rsne[j] = 1.f / sqrtf(nev[j]);
  const int ent0 = by * 128 + tx * 8;

  #pragma unroll
  for (int i = 0; i < 4; ++i) {
    const int tok = bx * 64 + ty * 4 + i;
    const float rsnz = 1.f / sqrtf(nzv[i]);
    float dist[8], simv[8];
    #pragma unroll
    for (int j = 0; j < 8; ++j) {
      dist[j] = (-2.f * acc[i][j] + nzv[i]) + nev[j];
      simv[j] = acc[i][j] * rsnz * rsne[j];
    }
    float* so = sim_out + (size_t)tok * 512 + ent0;
    *(float4*)&so[0] = make_float4(simv[0], simv[1], simv[2], simv[3]);
    *(float4*)&so[4] = make_float4(simv[4], simv[5], simv[6], simv[7]);

    float md = dist[0]; int mi = ent0;
    #pragma unroll
    for (int j = 1; j < 8; ++j)
      if (dist[j] < md) { md = dist[j]; mi = ent0 + j; }
    #pragma unroll
    for (int off = 1; off < 16; off <<= 1) {
      float od = __shfl_xor(md, off);
      int   oi = __shfl_xor(mi, off);
      if (od < md || (od == md && oi < mi)) { md = od; mi = oi; }
    }
    if (tx == 0) pmin[tok * 4 + by] = make_float2(md, (float)mi);
  }
}

// ---------------- vq_finish: z_e [c][t] reads; z_q out [tok][c] -----------
__global__ __launch_bounds__(256) void vq_finish_kernel(
    const float* __restrict__ ze, const float* __restrict__ cb,
    const float2* __restrict__ pmin, float* __restrict__ zq,
    float* __restrict__ ids_out, float* __restrict__ blocksum)
{
  const int tid = threadIdx.x;
  const int lane = tid & 63, wvid = tid >> 6;
  float lloss = 0.f;
  for (int it = 0; it < 16; ++it) {
    const int tok = blockIdx.x * 64 + wvid * 16 + it;
    float bd = 1e30f; int bi = 0;
    #pragma unroll
    for (int p = 0; p < 4; ++p) {
      float2 pr = pmin[tok * 4 + p];
      float d = pr.x; int i = (int)pr.y;
      if (d < bd || (d == bd && i < bi)) { bd = d; bi = i; }
    }
    const int bb_ = tok >> 13, tt_ = tok & 8191;
    float zev = ze[((size_t)bb_ * 64 + lane) * 8192 + tt_];   // same values
    float cv  = cb[(size_t)bi * 64 + lane];
    float df = zev - cv;
    float s = df * df;
    #pragma unroll
    for (int off = 32; off; off >>= 1) s += __shfl_down(s, off);
    zq[(size_t)tok * 64 + lane] = cv;
    if (lane == 0) { ids_out[tok] = (float)bi; lloss += sqrtf(s); }
  }
  __shared__ float ls[4];
  if (lane == 0) ls[wvid] = lloss;
  __syncthreads();
  if (tid == 0) blocksum[blockIdx.x] = ls[0] + ls[1] + ls[2] + ls[3];
}

__global__ void loss_fin_kernel(const float* __restrict__ blocksum,
                                float* __restrict__ out)
{
  const int lane = threadIdx.x;
  float s = 0.f;
  for (int i = lane; i < 512; i += 64) s += blocksum[i];
  #pragma unroll
  for (int off = 32; off; off >>= 1) s += __shfl_down(s, off);
  if (lane == 0) out[0] = 1.25f * s / 32768.f;
}

// ---------------------------------------------------------------------------
#define LAUNCH_CONV3CT(DILV, RESV, XP, WP, BP, RP, YP)                         \
  do {                                                                         \
    if (T >= 16384)                                                            \
      conv3ct_kernel<DILV, RESV, 128><<<dim3(T / 128, 4), 512, 0, stream>>>(   \
          XP, WP, BP, RP, YP, T);                                              \
    else                                                                       \
      conv3ct_kernel<DILV, RESV, 64><<<dim3(T / 64, 4), 512, 0, stream>>>(     \
          XP, WP, BP, RP, YP, T);                                              \
  } while (0)

#define LAUNCH_CONV3(DILV, RESV, XP, WP, BP, RP, YP)                           \
  do {                                                                         \
    if (T >= 16384)                                                            \
      conv3_kernel<DILV, RESV, 128><<<dim3(T / 128, 4), 512, 0, stream>>>(     \
          XP, WP, BP, RP, YP, T);                                              \
    else                                                                       \
      conv3_kernel<DILV, RESV, 64><<<dim3(T / 64, 4), 512, 0, stream>>>(       \
          XP, WP, BP, RP, YP, T);                                              \
  } while (0)

extern "C" void kernel_launch(void* const* d_in, const int* in_sizes, int n_in,
                              void* d_out, int out_size, void* d_ws, size_t ws_size,
                              hipStream_t stream)
{
  const float* x       = (const float*)d_in[0];
  const float* w_down0 = (const float*)d_in[1];
  const float* b_down0 = (const float*)d_in[2];
  const float* w_down  = (const float*)d_in[3];
  const float* b_down  = (const float*)d_in[4];
  const float* w_res_e = (const float*)d_in[5];
  const float* b_res_e = (const float*)d_in[6];
  const float* cb      = (const float*)d_in[7];
  const float* w_res_d = (const float*)d_in[8];
  const float* b_res_d = (const float*)d_in[9];
  const float* w_up    = (const float*)d_in[10];
  const float* b_up    = (const float*)d_in[11];
  const float* w_proj  = (const float*)d_in[12];
  const float* b_proj  = (const float*)d_in[13];

  float* out = (float*)d_out;
  const size_t BUF = (size_t)4 * 65536 * 64;
  float*  bufA     = (float*)d_ws;
  float*  bufB     = bufA + BUF;
  float*  nzbuf    = bufB + BUF;
  float*  nebuf    = nzbuf + 32768;
  float2* pmin     = (float2*)(nebuf + 512);
  float*  blocksum = (float*)(pmin + 32768 * 4);

  float* h = bufA;
  float* tmp = bufB;

  // ---- encoder (channel-major [b][c][t] intermediates) ----
  down0ct_kernel<<<dim3(128, 64, 4), 256, 0, stream>>>(x, w_down0, b_down0, h);
  int T = 32768;
  for (int blk = 0; blk < 3; ++blk) {
    if (blk > 0) {
      down2ct_kernel<<<dim3(T / 2 / 64, 4), 512, 0, stream>>>(
          h, w_down + (size_t)(blk - 1) * 4 * 64 * 64, b_down + (blk - 1) * 64, tmp, T);
      T >>= 1;
      float* s = h; h = tmp; tmp = s;
    }
    for (int r = 0; r < 4; ++r) {
      const float* w0p = w_res_e + (((size_t)blk * 4 + r) * 2 + 0) * 3 * 64 * 64;
      const float* w1p = w_res_e + (((size_t)blk * 4 + r) * 2 + 1) * 3 * 64 * 64;
      const float* b0p = b_res_e + (((size_t)blk * 4 + r) * 2 + 0) * 64;
      const float* b1p = b_res_e + (((size_t)blk * 4 + r) * 2 + 1) * 64;
      LAUNCH_CONV3CT(3, false, h, w0p, b0p, nullptr, tmp);
      LAUNCH_CONV3CT(1, true,  tmp, w1p, b1p, h, h);
    }
  }

  // ---- VQ (T == 8192; z_e in h as [b][c][8192]; 32768 tokens) ----
  nz_kernel<<<8192, 256, 0, stream>>>(h, nzbuf);
  ne_kernel<<<2, 256, 0, stream>>>(cb, nebuf);
  vq_dots_kernel<<<dim3(512, 4), 256, 0, stream>>>(h, cb, nzbuf, nebuf, out + OFF_SIM, pmin);
  vq_finish_kernel<<<512, 256, 0, stream>>>(h, cb, pmin, tmp, out + OFF_IDS, blocksum);
  loss_fin_kernel<<<1, 64, 0, stream>>>(blocksum, out + OFF_LOSS);
  { float* s = h; h = tmp; tmp = s; }  // h = z_q, [tok][c]

  // ---- decoder (r10 verbatim, [t][c] intermediates) ----
  for (int blk = 0; blk < 3; ++blk) {
    for (int r = 0; r < 4; ++r) {
      const float* w0p = w_res_d + (((size_t)blk * 4 + r) * 2 + 0) * 3 * 64 * 64;
      const float* w1p = w_res_d + (((size_t)blk * 4 + r) * 2 + 1) * 3 * 64 * 64;
      const float* b0p = b_res_d + (((size_t)blk * 4 + r) * 2 + 0) * 64;
      const float* b1p = b_res_d + (((size_t)blk * 4 + r) * 2 + 1) * 64;
      LAUNCH_CONV3(1, false, h, w0p, b0p, nullptr, tmp);
      LAUNCH_CONV3(3, true,  tmp, w1p, b1p, h, h);
    }
    up_kernel<<<dim3(2 * T / 128, 4), 512, 0, stream>>>(
        h, w_up + (size_t)blk * 4 * 64 * 64, b_up + blk * 64, tmp, T);
    T <<= 1;
    float* s = h; h = tmp; tmp = s;
  }

  // ---- final projection (T == 65536) ----
  proj_kernel<<<1024, 256, 0, stream>>>(h, w_proj, b_proj, out);
}